// Round 1
// 922.225 us; speedup vs baseline: 1.1475x; 1.1475x over previous
//
#include <hip/hip_runtime.h>

typedef unsigned short u16;
typedef unsigned int u32;
typedef unsigned long long u64;

#define N_SITES 500000
#define CIN 32
#define COUT 32
#define DD 128
#define HHH 128
#define WWW 128
#define KVOL 125
#define EPSV 1e-4f
#define NVOX (4*DD*HHH*WWW)           // 8,388,608 = 8192 * 1024
#define RED_BLOCKS 512
#define CNT_BLOCKS 8192
#define NSLOT 500224                  // 1954 * 256 (padded site slots)

typedef short v8s __attribute__((ext_vector_type(8)));
typedef float v4f __attribute__((ext_vector_type(4)));

// ---------- helpers ----------
__device__ __forceinline__ u16 f2bf(float f){
  union { float f; u32 i; } v; v.f = f;
  u32 r = v.i + 0x7fffu + ((v.i >> 16) & 1u);
  return (u16)(r >> 16);
}

// ---------- BN stage 1: per-block partial sums (f32 input) ----------
__launch_bounds__(256)
__global__ void bn_reduce(const float* __restrict__ x, float* __restrict__ partial){
  __shared__ float ssum[8][32], ssq[8][32];
  int tid = threadIdx.x;
  int c   = tid & 31;
  int row = tid >> 5;
  float s = 0.f, q = 0.f;
  for(int site = blockIdx.x*8 + row; site < N_SITES; site += gridDim.x*8){
    float f = x[(size_t)site*32 + c];
    s += f; q += f*f;
  }
  ssum[row][c] = s; ssq[row][c] = q;
  __syncthreads();
  if(tid < 32){
    float ts = 0.f, tq = 0.f;
    #pragma unroll
    for(int r = 0; r < 8; r++){ ts += ssum[r][tid]; tq += ssq[r][tid]; }
    partial[blockIdx.x*64 + tid]      = ts;
    partial[blockIdx.x*64 + 32 + tid] = tq;
  }
}

// ---------- BN stage 2: finalize scale/shift ----------
__global__ void bn_finalize(const float* __restrict__ partial, const float* __restrict__ gamma,
                            const float* __restrict__ beta, float* __restrict__ ss, int nblk){
  int tid = threadIdx.x;
  if(tid >= 32) return;
  float s = 0.f, q = 0.f;
  for(int b = 0; b < nblk; b++){
    s += partial[b*64 + tid];
    q += partial[b*64 + 32 + tid];
  }
  float mean = s / (float)N_SITES;
  float var  = q / (float)N_SITES - mean*mean;   // biased, matches reference
  float scale = gamma[tid] * rsqrtf(var + EPSV);
  ss[tid]      = scale;
  ss[32 + tid] = beta[tid] - mean*scale;
}

// ---------- y = bf16(relu(x*scale+shift)) into workspace ----------
__launch_bounds__(256)
__global__ void bn_apply_y(const float4* __restrict__ xv, const float* __restrict__ ss,
                           uint4* __restrict__ yv){
  __shared__ float sc[64];
  int tid = threadIdx.x;
  if(tid < 64) sc[tid] = ss[tid];
  __syncthreads();
  const int total = N_SITES*CIN/8;            // 2,000,000 chunks of 8
  int stride = gridDim.x*256;
  for(int i = blockIdx.x*256 + tid; i < total; i += stride){
    int c0 = (i & 3) * 8;
    float4 a = xv[2*i], b = xv[2*i+1];
    float f[8] = {a.x,a.y,a.z,a.w,b.x,b.y,b.z,b.w};
    #pragma unroll
    for(int j = 0; j < 8; j++) f[j] = fmaxf(f[j]*sc[c0+j] + sc[32+c0+j], 0.f);
    uint4 o;
    o.x = ((u32)f2bf(f[1])<<16) | f2bf(f[0]);
    o.y = ((u32)f2bf(f[3])<<16) | f2bf(f[2]);
    o.z = ((u32)f2bf(f[5])<<16) | f2bf(f[4]);
    o.w = ((u32)f2bf(f[7])<<16) | f2bf(f[6]);
    yv[i] = o;
  }
}

// ---------- scatter site indices into dense voxel grid ----------
__launch_bounds__(256)
__global__ void build_grid(const int4* __restrict__ coords, int* __restrict__ grid){
  int i = blockIdx.x*256 + threadIdx.x;
  if(i >= N_SITES) return;
  int4 c = coords[i];  // (b, z, y, x)
  grid[((c.x*DD + c.y)*HHH + c.z)*WWW + c.w] = i;
}

// ---------- per-1024-voxel-block active counts ----------
__launch_bounds__(256)
__global__ void count_blocks(const int* __restrict__ grid, int* __restrict__ blockcnt){
  int b = blockIdx.x, t = threadIdx.x;
  int cnt = 0;
  #pragma unroll
  for(int k = 0; k < 4; k++) cnt += (grid[b*1024 + k*256 + t] >= 0);
  #pragma unroll
  for(int o = 32; o > 0; o >>= 1) cnt += __shfl_down(cnt, o);
  __shared__ int wsum[4];
  if((t & 63) == 0) wsum[t >> 6] = cnt;
  __syncthreads();
  if(t == 0) blockcnt[b] = wsum[0] + wsum[1] + wsum[2] + wsum[3];
}

// ---------- exclusive prefix over 8192 block counts (one block) ----------
__launch_bounds__(1024)
__global__ void scan_blocks(const int* __restrict__ blockcnt, int* __restrict__ blockoff){
  __shared__ int s[1024];
  int t = threadIdx.x;
  int loc[8]; int v = 0;
  #pragma unroll
  for(int k = 0; k < 8; k++){ loc[k] = blockcnt[t*8 + k]; v += loc[k]; }
  s[t] = v; __syncthreads();
  for(int o = 1; o < 1024; o <<= 1){
    int add = (t >= o) ? s[t - o] : 0;
    __syncthreads();
    s[t] += add;
    __syncthreads();
  }
  int base = s[t] - v;
  #pragma unroll
  for(int k = 0; k < 8; k++){ blockoff[t*8 + k] = base; base += loc[k]; }
}

// ---------- ordered compaction: perm[j] = site ids in ascending voxel order ----------
__launch_bounds__(256)
__global__ void fill_perm(const int* __restrict__ grid, const int* __restrict__ blockoff,
                          int* __restrict__ perm){
  int b = blockIdx.x, t = threadIdx.x;
  int w = t >> 6, lane = t & 63;
  __shared__ int wcnt[4];
  __shared__ int carry;
  if(t == 0) carry = 0;
  __syncthreads();
  int base = blockoff[b];
  for(int p = 0; p < 4; p++){
    int v = b*1024 + p*256 + t;
    int s = grid[v];
    bool act = (s >= 0);
    u64 bal = __ballot(act);
    int pre = (int)__popcll(bal & ((1ull << lane) - 1ull));
    if(lane == 0) wcnt[w] = (int)__popcll(bal);
    __syncthreads();
    int woff = 0;
    for(int ww = 0; ww < w; ww++) woff += wcnt[ww];
    if(act) perm[base + carry + woff + pre] = s;
    int tot = wcnt[0] + wcnt[1] + wcnt[2] + wcnt[3];
    __syncthreads();
    if(t == 0) carry += tot;
    __syncthreads();
  }
}

// ---------- pad perm slots [N_SITES, NSLOT) with a valid site id ----------
__global__ void pad_perm(int* __restrict__ perm){
  int t = threadIdx.x;
  if(t < NSLOT - N_SITES) perm[N_SITES + t] = perm[0];
}

// ---------- pack W f32 [125][cin][cout] into bf16 MFMA B-fragment order ----------
// wf element index i = ((off*2 + tile)*64 + lane)*8 + j
// value = W[off][k][n], k=(lane>>4)*8+j, n=tile*16+(lane&15)
__launch_bounds__(256)
__global__ void prep_wfrag(const float* __restrict__ w, u16* __restrict__ wf){
  int i = blockIdx.x*256 + threadIdx.x;
  if(i >= KVOL*2*64*8) return;
  int j    = i & 7;
  int lane = (i >> 3) & 63;
  int tile = (i >> 9) & 1;
  int off  = i >> 10;
  int k = ((lane >> 4) << 3) + j;
  int n = (tile << 4) + (lane & 15);
  wf[i] = f2bf(w[off*1024 + k*32 + n]);
}

// ---------- submanifold sparse conv via MFMA gather-GEMM ----------
// wave = 64 voxel-sorted sites = 4 M-tiles of 16.
// v2: per dz-plane, batch all 25 grid probes into registers (branch-free
// clamped loads, 25 in flight) before any processing; weight-fragment loads
// hoisted above the ballot-skip; bijective XCD-aware block swizzle.
__launch_bounds__(256)
__global__ void conv_mfma(const u16* __restrict__ y, const int4* __restrict__ coords,
                          const u16* __restrict__ wf, const int* __restrict__ grid,
                          const int* __restrict__ perm, float* __restrict__ out){
  int t = threadIdx.x;
  int l = t & 63;
  int m15 = l & 15;
  int q = l >> 4;

  // bijective XCD swizzle: nwg = 8*q8 + r8; consecutive swz-blocks -> same XCD
  int nwg = gridDim.x;
  int bid = blockIdx.x;
  int xcd = bid & 7;
  int rank = bid >> 3;
  int q8 = nwg >> 3, r8 = nwg & 7;
  int swz = (xcd < r8 ? xcd*(q8+1) : r8*(q8+1) + (xcd - r8)*q8) + rank;

  int slot = swz*256 + t;                   // wave w owns slots [..+w*64, +64)
  int p = perm[slot];
  int4 c = coords[p];                       // (b, z, y, x)
  int Z = c.y, Y = c.z, X = c.w;
  int base = ((c.x*DD + Z)*HHH + Y)*WWW + X;

  // per-site x-validity (same for every (dz,dy) row)
  bool okx[5];
  #pragma unroll
  for(int k = 0; k < 5; k++) okx[k] = (u32)(X + k - 2) < WWW;

  const v8s vz8 = {0,0,0,0,0,0,0,0};
  v4f acc[4][2];
  #pragma unroll
  for(int g = 0; g < 4; g++){
    acc[g][0] = (v4f){0.f,0.f,0.f,0.f};
    acc[g][1] = (v4f){0.f,0.f,0.f,0.f};
  }

  const int HW = HHH*WWW;
  #pragma unroll 1
  for(int dz = -2; dz <= 2; dz++){
    bool okz = (u32)(Z + dz) < DD;
    int pb = base + dz*HW;

    // ---- probe phase: 25 independent clamped loads, all in flight ----
    int nv[25];
    #pragma unroll
    for(int r = 0; r < 5; r++){
      int rs = pb + (r-2)*WWW - 2;
      #pragma unroll
      for(int k = 0; k < 5; k++){
        int idx = rs + k;
        idx = idx < 0 ? 0 : idx;
        idx = idx > (NVOX-1) ? (NVOX-1) : idx;
        nv[r*5 + k] = grid[idx];            // value masked by ok below
      }
    }

    // ---- process phase ----
    int offb = (dz + 2) * 25;
    #pragma unroll
    for(int r = 0; r < 5; r++){
      bool okzy = okz & ((u32)(Y + r - 2) < HHH);
      #pragma unroll
      for(int k = 0; k < 5; k++){
        bool ok = okzy & okx[k];
        int nidx = ok ? nv[r*5 + k] : -1;
        u64 bal = __ballot(nidx >= 0);
        // weight fragments issued before the skip check (L2-hot, off-chain)
        const v8s* wfo = (const v8s*)(wf + (offb + r*5 + k)*1024);
        v8s b0 = wfo[l];
        v8s b1 = wfo[64 + l];
        if(bal == 0) continue;
        #pragma unroll
        for(int g = 0; g < 4; g++){
          if(((bal >> (g*16)) & 0xFFFFull) == 0) continue;
          int nid = __shfl(nidx, (g << 4) | m15);
          v8s a = vz8;
          if(nid >= 0) a = *(const v8s*)(y + (size_t)nid*32 + q*8);
          acc[g][0] = __builtin_amdgcn_mfma_f32_16x16x32_bf16(a, b0, acc[g][0], 0, 0, 0);
          acc[g][1] = __builtin_amdgcn_mfma_f32_16x16x32_bf16(a, b1, acc[g][1], 0, 0, 0);
        }
      }
    }
  }

  // epilogue: C/D layout col=lane&15, row=(lane>>4)*4+reg  [m89-verified]
  #pragma unroll
  for(int g = 0; g < 4; g++){
    #pragma unroll
    for(int r = 0; r < 4; r++){
      int row = q*4 + r;
      int s = __shfl(p, (g << 4) | row);
      out[(size_t)s*32 + m15]      = acc[g][0][r];
      out[(size_t)s*32 + 16 + m15] = acc[g][1][r];
    }
  }
}

extern "C" void kernel_launch(void* const* d_in, const int* in_sizes, int n_in,
                              void* d_out, int out_size, void* d_ws, size_t ws_size,
                              hipStream_t stream) {
  const float* feats  = (const float*)d_in[0];   // [N,32] f32
  const int4*  coords = (const int4*) d_in[1];   // [N,4] int32
  const float* gamma  = (const float*)d_in[2];   // [32] f32
  const float* beta   = (const float*)d_in[3];   // [32] f32
  const float* wght   = (const float*)d_in[4];   // [125,32,32] f32
  float* out = (float*)d_out;

  char* ws = (char*)d_ws;
  int*   grid     = (int*)  ws;                   // 33,554,432 B
  u16*   ybuf     = (u16*)  (ws + 33554432);      // 32,000,000 B
  u16*   wf       = (u16*)  (ws + 65554432);      //    256,000 B
  int*   perm     = (int*)  (ws + 65810432);      //  2,000,896 B
  int*   blockcnt = (int*)  (ws + 67811328);      //     32,768 B
  int*   blockoff = (int*)  (ws + 67844096);      //     32,768 B
  float* partial  = (float*)(ws + 67876864);      //    131,072 B
  float* ss       = (float*)(ws + 68007936);      //        256 B
  // total: 68,008,192 B (~64.9 MiB)

  hipMemsetAsync(grid, 0xFF, (size_t)NVOX*4, stream);      // grid = -1

  bn_reduce  <<<RED_BLOCKS, 256, 0, stream>>>(feats, partial);
  bn_finalize<<<1, 32, 0, stream>>>(partial, gamma, beta, ss, RED_BLOCKS);
  bn_apply_y <<<2048, 256, 0, stream>>>((const float4*)feats, ss, (uint4*)ybuf);

  build_grid  <<<(N_SITES+255)/256, 256, 0, stream>>>(coords, grid);
  count_blocks<<<CNT_BLOCKS, 256, 0, stream>>>(grid, blockcnt);
  scan_blocks <<<1, 1024, 0, stream>>>(blockcnt, blockoff);
  fill_perm   <<<CNT_BLOCKS, 256, 0, stream>>>(grid, blockoff, perm);
  pad_perm    <<<1, 256, 0, stream>>>(perm);

  prep_wfrag<<<(KVOL*2*64*8 + 255)/256, 256, 0, stream>>>(wght, wf);

  conv_mfma<<<NSLOT/256, 256, 0, stream>>>(ybuf, coords, wf, grid, perm, out);
}

// Round 2
// 649.512 us; speedup vs baseline: 1.6293x; 1.4199x over previous
//
#include <hip/hip_runtime.h>

typedef unsigned short u16;
typedef unsigned int u32;
typedef unsigned long long u64;

#define N_SITES 500000
#define CIN 32
#define COUT 32
#define DD 128
#define HHH 128
#define WWW 128
#define KVOL 125
#define EPSV 1e-4f
#define NVOX (4*DD*HHH*WWW)           // 8,388,608 = 8192 * 1024
#define RED_BLOCKS 504
#define CNT_BLOCKS 8192
#define NSLOT 500224                  // 1954 * 256 (padded site slots)
#define ZROW  N_SITES                 // zero feature row index in ybuf

typedef short v8s __attribute__((ext_vector_type(8)));
typedef float v4f __attribute__((ext_vector_type(4)));
typedef float v16f __attribute__((ext_vector_type(16)));

// ---------- helpers ----------
__device__ __forceinline__ u16 f2bf(float f){
  union { float f; u32 i; } v; v.f = f;
  u32 r = v.i + 0x7fffu + ((v.i >> 16) & 1u);
  return (u16)(r >> 16);
}

// ---------- BN stage 1: per-block partial sums (f32 input) ----------
__launch_bounds__(256)
__global__ void bn_reduce(const float* __restrict__ x, float* __restrict__ partial){
  __shared__ float ssum[8][32], ssq[8][32];
  int tid = threadIdx.x;
  int c   = tid & 31;
  int row = tid >> 5;
  float s = 0.f, q = 0.f;
  for(int site = blockIdx.x*8 + row; site < N_SITES; site += gridDim.x*8){
    float f = x[(size_t)site*32 + c];
    s += f; q += f*f;
  }
  ssum[row][c] = s; ssq[row][c] = q;
  __syncthreads();
  if(tid < 32){
    float ts = 0.f, tq = 0.f;
    #pragma unroll
    for(int r = 0; r < 8; r++){ ts += ssum[r][tid]; tq += ssq[r][tid]; }
    partial[blockIdx.x*64 + tid]      = ts;
    partial[blockIdx.x*64 + 32 + tid] = tq;
  }
}

// ---------- BN stage 2: finalize scale/shift ----------
__global__ void bn_finalize(const float* __restrict__ partial, const float* __restrict__ gamma,
                            const float* __restrict__ beta, float* __restrict__ ss, int nblk){
  int tid = threadIdx.x;
  if(tid >= 32) return;
  float s = 0.f, q = 0.f;
  for(int b = 0; b < nblk; b++){
    s += partial[b*64 + tid];
    q += partial[b*64 + 32 + tid];
  }
  float mean = s / (float)N_SITES;
  float var  = q / (float)N_SITES - mean*mean;   // biased, matches reference
  float scale = gamma[tid] * rsqrtf(var + EPSV);
  ss[tid]      = scale;
  ss[32 + tid] = beta[tid] - mean*scale;
}

// ---------- y = bf16(relu(x*scale+shift)) into workspace ----------
__launch_bounds__(256)
__global__ void bn_apply_y(const float4* __restrict__ xv, const float* __restrict__ ss,
                           uint4* __restrict__ yv){
  __shared__ float sc[64];
  int tid = threadIdx.x;
  if(tid < 64) sc[tid] = ss[tid];
  __syncthreads();
  const int total = N_SITES*CIN/8;            // 2,000,000 chunks of 8
  int stride = gridDim.x*256;
  for(int i = blockIdx.x*256 + tid; i < total; i += stride){
    int c0 = (i & 3) * 8;
    float4 a = xv[2*i], b = xv[2*i+1];
    float f[8] = {a.x,a.y,a.z,a.w,b.x,b.y,b.z,b.w};
    #pragma unroll
    for(int j = 0; j < 8; j++) f[j] = fmaxf(f[j]*sc[c0+j] + sc[32+c0+j], 0.f);
    uint4 o;
    o.x = ((u32)f2bf(f[1])<<16) | f2bf(f[0]);
    o.y = ((u32)f2bf(f[3])<<16) | f2bf(f[2]);
    o.z = ((u32)f2bf(f[5])<<16) | f2bf(f[4]);
    o.w = ((u32)f2bf(f[7])<<16) | f2bf(f[6]);
    yv[i] = o;
  }
}

// ---------- scatter site indices into dense voxel grid ----------
__launch_bounds__(256)
__global__ void build_grid(const int4* __restrict__ coords, int* __restrict__ grid){
  int i = blockIdx.x*256 + threadIdx.x;
  if(i >= N_SITES) return;
  int4 c = coords[i];  // (b, z, y, x)
  grid[((c.x*DD + c.y)*HHH + c.z)*WWW + c.w] = i;
}

// ---------- per-1024-voxel-block active counts ----------
__launch_bounds__(256)
__global__ void count_blocks(const int* __restrict__ grid, int* __restrict__ blockcnt){
  int b = blockIdx.x, t = threadIdx.x;
  int cnt = 0;
  #pragma unroll
  for(int k = 0; k < 4; k++) cnt += (grid[b*1024 + k*256 + t] >= 0);
  #pragma unroll
  for(int o = 32; o > 0; o >>= 1) cnt += __shfl_down(cnt, o);
  __shared__ int wsum[4];
  if((t & 63) == 0) wsum[t >> 6] = cnt;
  __syncthreads();
  if(t == 0) blockcnt[b] = wsum[0] + wsum[1] + wsum[2] + wsum[3];
}

// ---------- exclusive prefix over 8192 block counts (one block) ----------
__launch_bounds__(1024)
__global__ void scan_blocks(const int* __restrict__ blockcnt, int* __restrict__ blockoff){
  __shared__ int s[1024];
  int t = threadIdx.x;
  int loc[8]; int v = 0;
  #pragma unroll
  for(int k = 0; k < 8; k++){ loc[k] = blockcnt[t*8 + k]; v += loc[k]; }
  s[t] = v; __syncthreads();
  for(int o = 1; o < 1024; o <<= 1){
    int add = (t >= o) ? s[t - o] : 0;
    __syncthreads();
    s[t] += add;
    __syncthreads();
  }
  int base = s[t] - v;
  #pragma unroll
  for(int k = 0; k < 8; k++){ blockoff[t*8 + k] = base; base += loc[k]; }
}

// ---------- ordered compaction: perm[j] = site ids in ascending voxel order ----------
__launch_bounds__(256)
__global__ void fill_perm(const int* __restrict__ grid, const int* __restrict__ blockoff,
                          int* __restrict__ perm){
  int b = blockIdx.x, t = threadIdx.x;
  int w = t >> 6, lane = t & 63;
  __shared__ int wcnt[4];
  __shared__ int carry;
  if(t == 0) carry = 0;
  __syncthreads();
  int base = blockoff[b];
  for(int p = 0; p < 4; p++){
    int v = b*1024 + p*256 + t;
    int s = grid[v];
    bool act = (s >= 0);
    u64 bal = __ballot(act);
    int pre = (int)__popcll(bal & ((1ull << lane) - 1ull));
    if(lane == 0) wcnt[w] = (int)__popcll(bal);
    __syncthreads();
    int woff = 0;
    for(int ww = 0; ww < w; ww++) woff += wcnt[ww];
    if(act) perm[base + carry + woff + pre] = s;
    int tot = wcnt[0] + wcnt[1] + wcnt[2] + wcnt[3];
    __syncthreads();
    if(t == 0) carry += tot;
    __syncthreads();
  }
}

// ---------- pad perm slots; zero the sentinel feature row ----------
__global__ void pad_perm(int* __restrict__ perm, u32* __restrict__ yzero){
  int t = threadIdx.x;
  if(t < NSLOT - N_SITES) perm[N_SITES + t] = perm[0];
  if(t < 16) yzero[t] = 0;                    // 64 B zero row at ZROW
}

// ---------- pack W f32 [125][cin][cout] into bf16 32x32x16 B-fragment order ----------
// wf element index i = ((off*2 + half)*64 + lane)*8 + j
// value = W[off][k][n], k = half*16 + (lane>>5)*8 + j, n = lane&31
__launch_bounds__(256)
__global__ void prep_wfrag(const float* __restrict__ w, u16* __restrict__ wf){
  int i = blockIdx.x*256 + threadIdx.x;
  if(i >= KVOL*2*64*8) return;
  int j    = i & 7;
  int lane = (i >> 3) & 63;
  int half = (i >> 9) & 1;
  int off  = i >> 10;
  int k = half*16 + ((lane >> 5) << 3) + j;
  int n = lane & 31;
  wf[i] = f2bf(w[off*1024 + k*32 + n]);
}

// ---------- submanifold sparse conv via MFMA gather-GEMM ----------
// v3: 32x32x16 MFMA, 2 groups of 32 sites per wave. Each lane owns A-row
// (lane&31) of both groups (one-time init shfls); per-offset work is pure
// straight-line: sentinel-masked probe (grid[NVOX] = -1), zero-row gather
// (ybuf row ZROW = 0) — no ballots, no per-offset shuffles, no branches.
__launch_bounds__(256)
__global__ void conv_mfma(const u16* __restrict__ y, const int4* __restrict__ coords,
                          const u16* __restrict__ wf, const int* __restrict__ grid,
                          const int* __restrict__ perm, float* __restrict__ out){
  const char* __restrict__ yc  = (const char*)y;
  const char* __restrict__ wfc = (const char*)wf;
  const char* __restrict__ gc  = (const char*)grid;
  int t = threadIdx.x;
  int l = t & 63;
  int r31 = l & 31;
  int h = l >> 5;
  u32 koff = (u32)h << 4;          // A k-half byte offset within a 64B row
  u32 wl16 = (u32)l << 4;          // wf lane byte offset

  // bijective XCD swizzle
  int nwg = gridDim.x, bid = blockIdx.x;
  int xcd = bid & 7, rank = bid >> 3;
  int q8 = nwg >> 3, r8 = nwg & 7;
  int swz = (xcd < r8 ? xcd*(q8+1) : r8*(q8+1) + (xcd - r8)*q8) + rank;

  int slot = swz*256 + t;
  int p = perm[slot];
  int4 c = coords[p];                       // (b, z, y, x)
  int Z = c.y, Y = c.z, X = c.w;
  int base = ((c.x*DD + Z)*HHH + Y)*WWW + X;

  // per-group A-row site parameters (one-time redistribution)
  int b0 = __shfl(base, r31);
  int b1 = __shfl(base, 32 + r31);
  int x0 = __shfl(X, r31),  x1 = __shfl(X, 32 + r31);
  int y0 = __shfl(Y, r31),  y1 = __shfl(Y, 32 + r31);
  int z0 = __shfl(Z, r31),  z1 = __shfl(Z, 32 + r31);

  bool okx0[5], okx1[5], oky0[5], oky1[5];
  #pragma unroll
  for(int k = 0; k < 5; k++){
    okx0[k] = (u32)(x0 + k - 2) < WWW;
    okx1[k] = (u32)(x1 + k - 2) < WWW;
    oky0[k] = (u32)(y0 + k - 2) < HHH;
    oky1[k] = (u32)(y1 + k - 2) < HHH;
  }

  v16f acc0, acc1;
  #pragma unroll
  for(int i = 0; i < 16; i++){ acc0[i] = 0.f; acc1[i] = 0.f; }

  const int HW = HHH*WWW;
  #pragma unroll 1
  for(int dz = -2; dz <= 2; dz++){
    bool okz0 = (u32)(z0 + dz) < DD;
    bool okz1 = (u32)(z1 + dz) < DD;
    int pb0 = b0 + dz*HW, pb1 = b1 + dz*HW;

    // ---- probe phase: 50 independent sentinel-masked loads in flight ----
    int nv0[25], nv1[25];
    #pragma unroll
    for(int r = 0; r < 5; r++){
      bool zy0 = okz0 && oky0[r];
      bool zy1 = okz1 && oky1[r];
      #pragma unroll
      for(int k = 0; k < 5; k++){
        int d = (r-2)*WWW + (k-2);
        u32 a0 = (zy0 && okx0[k]) ? (u32)(pb0 + d) : (u32)NVOX;
        u32 a1 = (zy1 && okx1[k]) ? (u32)(pb1 + d) : (u32)NVOX;
        nv0[r*5+k] = *(const int*)(gc + a0*4u);   // grid[NVOX] = -1 sentinel
        nv1[r*5+k] = *(const int*)(gc + a1*4u);
      }
    }

    // ---- process phase: branch-free straight line ----
    u32 wplane = (u32)((dz + 2) * 25) * 2048u + wl16;
    #pragma unroll
    for(int o = 0; o < 25; o++){
      u32 wo = wplane + (u32)(o * 2048);
      v8s wb0 = *(const v8s*)(wfc + wo);           // k 0..15
      v8s wb1 = *(const v8s*)(wfc + wo + 1024u);   // k 16..31

      int n0 = nv0[o];
      int rw0 = n0 >= 0 ? n0 : ZROW;               // invalid -> zero row
      u32 ya0 = ((u32)rw0 << 6) + koff;
      v8s a00 = *(const v8s*)(yc + ya0);
      v8s a01 = *(const v8s*)(yc + ya0 + 32u);
      acc0 = __builtin_amdgcn_mfma_f32_32x32x16_bf16(a00, wb0, acc0, 0, 0, 0);
      acc0 = __builtin_amdgcn_mfma_f32_32x32x16_bf16(a01, wb1, acc0, 0, 0, 0);

      int n1 = nv1[o];
      int rw1 = n1 >= 0 ? n1 : ZROW;
      u32 ya1 = ((u32)rw1 << 6) + koff;
      v8s a10 = *(const v8s*)(yc + ya1);
      v8s a11 = *(const v8s*)(yc + ya1 + 32u);
      acc1 = __builtin_amdgcn_mfma_f32_32x32x16_bf16(a10, wb0, acc1, 0, 0, 0);
      acc1 = __builtin_amdgcn_mfma_f32_32x32x16_bf16(a11, wb1, acc1, 0, 0, 0);
    }
  }

  // epilogue: C/D layout col=lane&31, row=(reg&3)+8*(reg>>2)+4*(lane>>5)  [m74/m101]
  #pragma unroll
  for(int rg = 0; rg < 16; rg++){
    int row = (rg & 3) + ((rg >> 2) << 3) + (h << 2);
    int s0 = __shfl(p, row);
    int s1 = __shfl(p, 32 + row);
    out[(size_t)s0*32 + r31] = acc0[rg];
    out[(size_t)s1*32 + r31] = acc1[rg];
  }
}

extern "C" void kernel_launch(void* const* d_in, const int* in_sizes, int n_in,
                              void* d_out, int out_size, void* d_ws, size_t ws_size,
                              hipStream_t stream) {
  const float* feats  = (const float*)d_in[0];   // [N,32] f32
  const int4*  coords = (const int4*) d_in[1];   // [N,4] int32
  const float* gamma  = (const float*)d_in[2];   // [32] f32
  const float* beta   = (const float*)d_in[3];   // [32] f32
  const float* wght   = (const float*)d_in[4];   // [125,32,32] f32
  float* out = (float*)d_out;

  char* ws = (char*)d_ws;
  int*   grid     = (int*)  ws;                   // 33,554,496 B (NVOX+1 ints, padded)
  u16*   ybuf     = (u16*)  (ws + 33554496);      // 32,000,064 B (500001 rows)
  u16*   wf       = (u16*)  (ws + 65554560);      //    256,000 B
  int*   perm     = (int*)  (ws + 65810560);      //  2,000,896 B
  int*   blockcnt = (int*)  (ws + 67811456);      //     32,768 B
  int*   blockoff = (int*)  (ws + 67844224);      //     32,768 B
  float* partial  = (float*)(ws + 67876992);      //    129,024 B
  float* ss       = (float*)(ws + 68006016);      //        256 B
  // total: 68,006,272 B (<= previous 68,008,192 footprint)

  hipMemsetAsync(grid, 0xFF, (size_t)NVOX*4 + 4, stream);   // grid = -1, incl. sentinel

  bn_reduce  <<<RED_BLOCKS, 256, 0, stream>>>(feats, partial);
  bn_finalize<<<1, 32, 0, stream>>>(partial, gamma, beta, ss, RED_BLOCKS);
  bn_apply_y <<<2048, 256, 0, stream>>>((const float4*)feats, ss, (uint4*)ybuf);

  build_grid  <<<(N_SITES+255)/256, 256, 0, stream>>>(coords, grid);
  count_blocks<<<CNT_BLOCKS, 256, 0, stream>>>(grid, blockcnt);
  scan_blocks <<<1, 1024, 0, stream>>>(blockcnt, blockoff);
  fill_perm   <<<CNT_BLOCKS, 256, 0, stream>>>(grid, blockoff, perm);
  pad_perm    <<<1, 256, 0, stream>>>(perm, (u32*)(ybuf + (size_t)ZROW*32));

  prep_wfrag<<<(KVOL*2*64*8 + 255)/256, 256, 0, stream>>>(wght, wf);

  conv_mfma<<<NSLOT/256, 256, 0, stream>>>(ybuf, coords, wf, grid, perm, out);
}